// Round 16
// baseline (108.013 us; speedup 1.0000x reference)
//
#include <hip/hip_runtime.h>
#include <hip/hip_bf16.h>

// Match numpy float32 semantics exactly: no FMA contraction, fixed op order.
#pragma clang fp contract(off)

#define B_ 8
#define N_ 4096
#define C_ 128
#define CH 64      // c's per B-pass (2 passes over c-halves)
#define K_ 16      // SAMPLE (output neighbors)
#define S_ 20      // SAMPLE_NUM (ball_query nsample)
#define NW 8       // queries per block (1 slice-scan per wave) -> 4096 blocks
#define R_ (NW * K_)   // 128 rows in transpose buffer
#define TP 65      // tbuf row pitch (odd -> stage writes ~2-way)
#define THREADS 512

typedef float f4 __attribute__((ext_vector_type(4)));

// slot s in [0,20) -> output position k = s - 1 - s/5, valid iff s>0 && s%5!=0

__global__ __launch_bounds__(THREADS, 6) void fused_kernel(const float* __restrict__ xyz,
                                                           const float* __restrict__ feat,
                                                           float* __restrict__ out_xyz,
                                                           float* __restrict__ out_feat) {
#pragma clang fp contract(off)
    // smem: B-phase transpose buffer ONLY (A is register-resident now)
    __shared__ __align__(16) float smem[R_ * TP];
    __shared__ int sidx[NW * K_];
    __shared__ int cb[NW][NW];   // per-query per-wave hit counts
    __shared__ int fb[NW][NW];   // per-query per-wave first in-slice hit

    const int w    = blockIdx.x;        // 0..4095
    const int b    = w & 7;             // XCD-align: batch b lives on XCD b
    const int n0   = (w >> 3) * NW;
    const int t    = threadIdx.x;
    const int wave = t >> 6;            // 0..7
    const int lane = t & 63;
    const float* xb = xyz + (size_t)b * (N_ * 3);
    const unsigned long long below = (1ull << lane) - 1ull;

    // ---- load this wave's 512-candidate slice into registers (once) --------
    // cand m = 512*wave + 64*i + lane; sq in exact reference op order
    float cx[8], cy[8], cz[8], cw[8];
#pragma unroll
    for (int i = 0; i < 8; ++i) {
        const int m = 512 * wave + 64 * i + lane;
        cx[i] = xb[m * 3 + 0];
        cy[i] = xb[m * 3 + 1];
        cz[i] = xb[m * 3 + 2];
        cw[i] = (cx[i] * cx[i] + cy[i] * cy[i]) + cz[i] * cz[i];
    }

    // ---------------- Phase A: 8 queries, slice-parallel across waves -------
    for (int q = 0; q < NW; ++q) {
        const int n = n0 + q;
        const float qx = xb[n * 3 + 0];
        const float qy = xb[n * 3 + 1];
        const float qz = xb[n * 3 + 2];
        const float sqn = (qx * qx + qy * qy) + qz * qz;   // exact ref op order

        unsigned long long M[8];
        int mycnt = 0;
#pragma unroll
        for (int i = 0; i < 8; ++i) {
            const float dt = (qx * cx[i] + qy * cy[i]) + qz * cz[i];
            const float d2 = (sqn + cw[i]) - 2.0f * dt;
            M[i] = __ballot(d2 < 256.0f);
            mycnt += (int)__popcll(M[i]);
        }
        // in-slice first hit (i-major order), wave-uniform
        int sfirst = 1 << 30;
#pragma unroll
        for (int i = 0; i < 8; ++i) {
            if (sfirst == (1 << 30) && M[i])
                sfirst = 64 * i + (int)__builtin_ctzll(M[i]);
        }

        if (lane == 0) { cb[q][wave] = mycnt; fb[q][wave] = sfirst; }
        __syncthreads();   // counts/firsts visible

        // prefix over lower slices; total; global first
        int pre = 0, tot = 0, fw = -1, ffi = 0;
#pragma unroll
        for (int wj = 0; wj < NW; ++wj) {
            const int cj = cb[q][wj];
            if (wj < wave) pre += cj;
            if (fw < 0 && cj > 0) { fw = wj; ffi = fb[q][wj]; }
            tot += cj;
        }
        const int firstg = 512 * fw + ffi;   // tot >= 1 always (self-hit)

        int* out = sidx + q * K_;
        if (pre < S_) {   // wave-uniform: slices past slot 20 skip entirely
            int run = pre;
#pragma unroll
            for (int i = 0; i < 8; ++i) {
                if (M[i]) {   // wave-uniform skip of empty 64-blocks
                    const int s = run + (int)__popcll(M[i] & below);
                    if (((M[i] >> lane) & 1) && s > 0 && s < S_ && (s % 5) != 0)
                        out[s - 1 - s / 5] = 512 * wave + 64 * i + lane;
                    run += (int)__popcll(M[i]);
                }
            }
        }
        // pad slots [tot, 20) with global first (wave q owns query q's pads)
        if (wave == q && lane < S_ && lane >= tot && lane > 0 && (lane % 5) != 0)
            out[lane - 1 - lane / 5] = firstg;
    }
    __syncthreads();   // sidx complete

    // ---------------- xyz gather (global scattered reads, L2-hot) -----------
    if (t < 3 * NW * K_) {                 // 384 threads
        const int j  = t >> 7;             // 0..2
        const int r  = t & 127;
        const int nl = r >> 4;             // 0..7
        const int k  = r & 15;
        __builtin_nontemporal_store(
            xb[(size_t)sidx[nl * K_ + k] * 3 + j],
            &out_xyz[((size_t)(b * 3 + j) * N_ + (n0 + nl)) * K_ + k]);
    }

    // ---------------- feature gather: 2 c-half passes, reg-pipelined --------
    // (byte-identical to R14: 512-B contiguous nt bursts per (c, pass))
    const float* fb_ = feat + (size_t)b * N_ * C_;
    float* ob = out_feat + (size_t)b * C_ * N_ * K_ + (size_t)n0 * K_;

    f4 v0, v1, v2, v3;
    const int sr0 = t >> 4,            scl = (t & 15) * 4;
    const int sr1 = (t + 512) >> 4;
    const int sr2 = (t + 1024) >> 4;
    const int sr3 = (t + 1536) >> 4;

#define LOADREGS(H)                                                             \
    do {                                                                        \
        const int cg = (H) * CH + scl;                                          \
        v0 = *reinterpret_cast<const f4*>(fb_ + (size_t)sidx[sr0] * C_ + cg);   \
        v1 = *reinterpret_cast<const f4*>(fb_ + (size_t)sidx[sr1] * C_ + cg);   \
        v2 = *reinterpret_cast<const f4*>(fb_ + (size_t)sidx[sr2] * C_ + cg);   \
        v3 = *reinterpret_cast<const f4*>(fb_ + (size_t)sidx[sr3] * C_ + cg);   \
    } while (0)

    LOADREGS(0);   // prologue (reads sidx + global only; smem untouched)

    for (int h = 0; h < 2; ++h) {
        __syncthreads();   // previous drain (or phase A) done with smem
        // commit pass h from regs into tbuf[r][cl..cl+3]
        smem[sr0 * TP + scl + 0] = v0.x; smem[sr0 * TP + scl + 1] = v0.y;
        smem[sr0 * TP + scl + 2] = v0.z; smem[sr0 * TP + scl + 3] = v0.w;
        smem[sr1 * TP + scl + 0] = v1.x; smem[sr1 * TP + scl + 1] = v1.y;
        smem[sr1 * TP + scl + 2] = v1.z; smem[sr1 * TP + scl + 3] = v1.w;
        smem[sr2 * TP + scl + 0] = v2.x; smem[sr2 * TP + scl + 1] = v2.y;
        smem[sr2 * TP + scl + 2] = v2.z; smem[sr2 * TP + scl + 3] = v2.w;
        smem[sr3 * TP + scl + 0] = v3.x; smem[sr3 * TP + scl + 1] = v3.y;
        smem[sr3 * TP + scl + 2] = v3.z; smem[sr3 * TP + scl + 3] = v3.w;

        if (h == 0) LOADREGS(1);   // L2 latency hides under drain of pass 0

        __syncthreads();
        // drain: e -> cl = e>>5 (0..63), r4 = (e&31)*4; 32 consecutive lanes
        // cover 512 contiguous bytes of one c-stream; nt f4 stores.
        for (int e = t; e < CH * R_ / 4; e += THREADS) {   // 2048 f4
            const int cl = e >> 5;
            const int r4 = (e & 31) * 4;
            f4 v;
            v.x = smem[(r4 + 0) * TP + cl];
            v.y = smem[(r4 + 1) * TP + cl];
            v.z = smem[(r4 + 2) * TP + cl];
            v.w = smem[(r4 + 3) * TP + cl];
            __builtin_nontemporal_store(
                v, reinterpret_cast<f4*>(
                       ob + (size_t)(h * CH + cl) * (N_ * K_) + r4));
        }
    }
#undef LOADREGS
}

extern "C" void kernel_launch(void* const* d_in, const int* in_sizes, int n_in,
                              void* d_out, int out_size, void* d_ws, size_t ws_size,
                              hipStream_t stream) {
    const float* xyz  = (const float*)d_in[0];   // (8, 4096, 3)
    const float* feat = (const float*)d_in[1];   // (8, 4096, 128)

    float* out_xyz  = (float*)d_out;                       // (8,3,4096,16)
    float* out_feat = out_xyz + (size_t)B_ * 3 * N_ * K_;  // (8,128,4096,16)

    // one block per (b, 8 consecutive queries); fused, no workspace
    hipLaunchKernelGGL(fused_kernel, dim3(B_ * N_ / NW), dim3(THREADS), 0, stream,
                       xyz, feat, out_xyz, out_feat);
}

// Round 17
// 64.885 us; speedup vs baseline: 1.6647x; 1.6647x over previous
//
#include <hip/hip_runtime.h>
#include <hip/hip_bf16.h>

// Match numpy float32 semantics exactly: no FMA contraction, fixed op order.
#pragma clang fp contract(off)

#define B_ 8
#define N_ 4096
#define HALF 2048  // points staged per A-pass (2 passes)
#define C_ 128
#define CH 64      // c's per B-pass (2 passes over c-halves)
#define K_ 16      // SAMPLE (output neighbors)
#define S_ 20      // SAMPLE_NUM (ball_query nsample)
#define NW 8       // queries per block (1 per wave) -> 4096 blocks, phase mixing
#define R_ (NW * K_)   // 128 rows in transpose buffer
#define TP 65      // tbuf row pitch (odd -> stage writes ~2-way)
#define THREADS 512

typedef float f4 __attribute__((ext_vector_type(4)));

// LDS-only barrier: drain own LDS ops (lgkmcnt) then s_barrier, WITHOUT the
// vmcnt(0) drain __syncthreads() forces. All inter-wave communication in this
// kernel is through LDS; global nt stores are write-only to disjoint addrs,
// so they may legally stay in flight across barriers (keeps the store pipe
// saturated across pass boundaries instead of emptying it each pass).
__device__ __forceinline__ void lds_barrier() {
    asm volatile("s_waitcnt lgkmcnt(0)" ::: "memory");
    __builtin_amdgcn_s_barrier();
    asm volatile("" ::: "memory");
}

// slot s in [0,20) -> output position k = s - 1 - s/5, valid iff s>0 && s%5!=0

__global__ __launch_bounds__(THREADS, 8) void fused_kernel(const float* __restrict__ xyz,
                                                           const float* __restrict__ feat,
                                                           float* __restrict__ out_xyz,
                                                           float* __restrict__ out_feat) {
#pragma clang fp contract(off)
    // ~33 KB union: phase A = packed (x,y,z,sq) half-batch (8192 floats);
    // phase B = transpose buffer [128 r][65 pitch] = 8320 floats
    __shared__ __align__(16) float smem[R_ * TP];
    __shared__ int sidx[NW * K_];
    f4* const pts = reinterpret_cast<f4*>(smem);

    const int w    = blockIdx.x;        // 0..4095
    const int b    = w & 7;             // XCD-align: batch b lives on XCD b
    const int n0   = (w >> 3) * NW;
    const int t    = threadIdx.x;
    const int wave = t >> 6;            // 0..7
    const int lane = t & 63;
    const float* xb = xyz + (size_t)b * (N_ * 3);

    // ---------------- Phase A: 1 query per wave, two staged halves ----------
    // (exact R12/R14 structure -- proven best A form, bit-exact vs reference)
    {
        const int n  = n0 + wave;
        const float qx = xb[n * 3 + 0];
        const float qy = xb[n * 3 + 1];
        const float qz = xb[n * 3 + 2];
        const float sqn = (qx * qx + qy * qy) + qz * qz;   // exact ref op order

        int cnt = 0;
        int first = -1;
        bool done = false;
        int* out = sidx + wave * K_;
        const unsigned long long below = (1ull << lane) - 1ull;

        for (int half = 0; half < 2; ++half) {
            lds_barrier();   // prior half's scan reads complete (no-op @ 0)
            // stage packed (x,y,z,sq); sq computed once, exact ref op order
            for (int p = t; p < HALF; p += THREADS) {
                const int gp = half * HALF + p;
                const float x = xb[gp * 3 + 0];
                const float y = xb[gp * 3 + 1];
                const float z = xb[gp * 3 + 2];
                const float sq = (x * x + y * y) + z * z;
                f4 v; v.x = x; v.y = y; v.z = z; v.w = sq;
                pts[p] = v;              // stride-16B across lanes: conflict-free
            }
            lds_barrier();               // half staged

            if (done) continue;          // wave-uniform; still hits barriers

            for (int base = 0; base < HALF; base += 512) {
                const int gbase = half * HALF + base;
                bool in[8];
                unsigned long long M[8];
#pragma unroll
                for (int i = 0; i < 8; ++i) {
                    const f4 P = pts[base + 64 * i + lane];   // 1 b128, no conflict
                    const float dt = (qx * P.x + qy * P.y) + qz * P.z;
                    const float d2 = (sqn + P.w) - 2.0f * dt;
                    in[i] = d2 < 256.0f;
                    M[i]  = __ballot(in[i]);
                }

                if (cnt == 0) {   // wave-uniform: global first in-ball index
                    int f = 0x7fffffff;
#pragma unroll
                    for (int i = 0; i < 8; ++i) {
                        if (M[i]) {
                            const int c = gbase + 64 * i + (int)__builtin_ctzll(M[i]);
                            f = f < c ? f : c;
                        }
                    }
                    if (f != 0x7fffffff) first = f;
                }

                // in-order slots: candidate index = gbase + 64*i + lane (i-major)
                int run = cnt;
#pragma unroll
                for (int i = 0; i < 8; ++i) {
                    const int s = run + (int)__popcll(M[i] & below);
                    if (in[i] && s > 0 && s < S_ && (s % 5) != 0)
                        out[s - 1 - s / 5] = gbase + 64 * i + lane;
                    run += (int)__popcll(M[i]);
                }
                cnt = run;
                if (cnt >= S_) { done = true; break; }   // wave-uniform
            }
        }

        // pad slots [cnt, 20) with 'first'
        if (lane < S_ && lane >= cnt && lane > 0 && (lane % 5) != 0) {
            out[lane - 1 - lane / 5] = first;
        }
    }
    lds_barrier();   // sidx complete; all scan reads of smem done

    // ---------------- xyz gather (global scattered reads, L2-hot) -----------
    if (t < 3 * NW * K_) {                 // 384 threads
        const int j  = t >> 7;             // 0..2
        const int r  = t & 127;
        const int nl = r >> 4;             // 0..7
        const int k  = r & 15;
        __builtin_nontemporal_store(
            xb[(size_t)sidx[nl * K_ + k] * 3 + j],
            &out_xyz[((size_t)(b * 3 + j) * N_ + (n0 + nl)) * K_ + k]);
    }

    // ---------------- feature gather: 2 c-half passes, reg-pipelined --------
    // (byte-identical layout to R14: 512-B contiguous nt bursts per (c, pass))
    const float* fb = feat + (size_t)b * N_ * C_;
    float* ob = out_feat + (size_t)b * C_ * N_ * K_ + (size_t)n0 * K_;

    f4 v0, v1, v2, v3;
    const int sr0 = t >> 4,            scl = (t & 15) * 4;
    const int sr1 = (t + 512) >> 4;
    const int sr2 = (t + 1024) >> 4;
    const int sr3 = (t + 1536) >> 4;

#define LOADREGS(H)                                                             \
    do {                                                                        \
        const int cg = (H) * CH + scl;                                          \
        v0 = *reinterpret_cast<const f4*>(fb + (size_t)sidx[sr0] * C_ + cg);    \
        v1 = *reinterpret_cast<const f4*>(fb + (size_t)sidx[sr1] * C_ + cg);    \
        v2 = *reinterpret_cast<const f4*>(fb + (size_t)sidx[sr2] * C_ + cg);    \
        v3 = *reinterpret_cast<const f4*>(fb + (size_t)sidx[sr3] * C_ + cg);    \
    } while (0)

    LOADREGS(0);   // prologue (reads sidx + global only; smem untouched)

    for (int h = 0; h < 2; ++h) {
        lds_barrier();   // previous drain (or phase A) done with smem
        // commit pass h from regs into tbuf[r][cl..cl+3]
        smem[sr0 * TP + scl + 0] = v0.x; smem[sr0 * TP + scl + 1] = v0.y;
        smem[sr0 * TP + scl + 2] = v0.z; smem[sr0 * TP + scl + 3] = v0.w;
        smem[sr1 * TP + scl + 0] = v1.x; smem[sr1 * TP + scl + 1] = v1.y;
        smem[sr1 * TP + scl + 2] = v1.z; smem[sr1 * TP + scl + 3] = v1.w;
        smem[sr2 * TP + scl + 0] = v2.x; smem[sr2 * TP + scl + 1] = v2.y;
        smem[sr2 * TP + scl + 2] = v2.z; smem[sr2 * TP + scl + 3] = v2.w;
        smem[sr3 * TP + scl + 0] = v3.x; smem[sr3 * TP + scl + 1] = v3.y;
        smem[sr3 * TP + scl + 2] = v3.z; smem[sr3 * TP + scl + 3] = v3.w;

        if (h == 0) LOADREGS(1);   // L2 latency hides under drain of pass 0

        lds_barrier();
        // drain: e -> cl = e>>5 (0..63), r4 = (e&31)*4; 32 consecutive lanes
        // cover 512 contiguous bytes of one c-stream; nt f4 stores.
        for (int e = t; e < CH * R_ / 4; e += THREADS) {   // 2048 f4
            const int cl = e >> 5;
            const int r4 = (e & 31) * 4;
            f4 v;
            v.x = smem[(r4 + 0) * TP + cl];
            v.y = smem[(r4 + 1) * TP + cl];
            v.z = smem[(r4 + 2) * TP + cl];
            v.w = smem[(r4 + 3) * TP + cl];
            __builtin_nontemporal_store(
                v, reinterpret_cast<f4*>(
                       ob + (size_t)(h * CH + cl) * (N_ * K_) + r4));
        }
    }
#undef LOADREGS
}

extern "C" void kernel_launch(void* const* d_in, const int* in_sizes, int n_in,
                              void* d_out, int out_size, void* d_ws, size_t ws_size,
                              hipStream_t stream) {
    const float* xyz  = (const float*)d_in[0];   // (8, 4096, 3)
    const float* feat = (const float*)d_in[1];   // (8, 4096, 128)

    float* out_xyz  = (float*)d_out;                       // (8,3,4096,16)
    float* out_feat = out_xyz + (size_t)B_ * 3 * N_ * K_;  // (8,128,4096,16)

    // one block per (b, 8 consecutive queries); fused, no workspace
    hipLaunchKernelGGL(fused_kernel, dim3(B_ * N_ / NW), dim3(THREADS), 0, stream,
                       xyz, feat, out_xyz, out_feat);
}